// Round 17
// baseline (120.912 us; speedup 1.0000x reference)
//
#include <hip/hip_runtime.h>
#include <math.h>

// Deepmd angular descriptor, f32 in / f32 out. B=8, N=4096, M=96, OUT_W=384.
//
// R17 = R16 (compile-fixed): nontemporal hints on the never-re-read 49 MB
// output write stream and the read-once nbr/mask streams. R16 failed to
// compile: __builtin_nontemporal_store rejects HIP_vector_type (float4 is a
// struct). Use clang ext_vector_type floats (true vectors) for NT data.
// Everything else identical to R15 (~29 us): dense full-wave loads (2 pairs
// = 192 contiguous items = 3/lane), 64 KB LDS position table, in-register
// ballot/popc stable rank, register merge, one 16B+8B store per row.
#define M_NB   96
#define OUT_W  384
#define NATOM  4096
#define WPB    16
#define LOWM   0x00000000FFFFFFFFull
#define HIGHM  0xFFFFFFFF00000000ull

typedef float vf4 __attribute__((ext_vector_type(4)));
typedef float vf2 __attribute__((ext_vector_type(2)));

// fold one item (row floats [base,base+3)) into this lane's output slots:
// vf4 owns [4*lane,4*lane+4), vf2 owns [256+2*lane,256+2*lane+2)
__device__ __forceinline__ void merge3(vf4& a4, vf2& a2, int base,
                                       float v0, float v1, float v2, int lane)
{
    const int f4lo = 4 * lane;
    const int f2lo = 256 + 2 * lane;
    const float v[3] = {v0, v1, v2};
    #pragma unroll
    for (int t = 0; t < 3; ++t) {
        const int idx = base + t;
        if      (idx == f4lo)     a4.x = v[t];
        else if (idx == f4lo + 1) a4.y = v[t];
        else if (idx == f4lo + 2) a4.z = v[t];
        else if (idx == f4lo + 3) a4.w = v[t];
        else if (idx == f2lo)     a2.x = v[t];
        else if (idx == f2lo + 1) a2.y = v[t];
    }
}

__global__ __launch_bounds__(64 * WPB, 8) void deepmd_angular_kernel(
    const float* __restrict__ positions,  // [B,N,3]
    const float* __restrict__ cell,       // [B,3,3]
    const float* __restrict__ offsets,    // [B,N,M,3]
    const float* __restrict__ mask,       // [B,N,M]
    const int*   __restrict__ neighbors,  // [B,N,M]
    float*       __restrict__ out,        // [B,N,OUT_W]
    int N)
{
    __shared__ float4 pos4_s[NATOM];        // 64 KB padded position table

    const int tid  = threadIdx.x;
    const int wv   = tid >> 6;
    const int lane = tid & 63;

    const int p0 = blockIdx.x * (WPB * 4);       // 64 pairs per block
    const int b  = p0 / N;                       // uniform (64 | N)

    // ---- stage batch positions -> LDS (padded to 16 B/atom) ----
    {
        const float* pb_ = positions + (size_t)b * N * 3;
        for (int a = tid; a < NATOM; a += 64 * WPB) {
            const float3 v = *(const float3*)(pb_ + 3 * a);
            pos4_s[a] = make_float4(v.x, v.y, v.z, 0.f);
        }
    }
    __syncthreads();                             // only barrier in the kernel

    const float* cb = cell + (size_t)b * 9;      // uniform -> scalar loads
    const float c00 = cb[0], c01 = cb[1], c02 = cb[2];
    const float c10 = cb[3], c11 = cb[4], c12 = cb[5];
    const float c20 = cb[6], c21 = cb[7], c22 = cb[8];

    #pragma unroll
    for (int it = 0; it < 2; ++it) {
        const int q0   = p0 + wv * 4 + it * 2;   // first of this wave's 2 pairs
        const long base = (long)q0 * M_NB;       // contiguous 192 elements
        const long e0 = base + lane, e1 = e0 + 64, e2 = e0 + 128;

        // ---- dense full-wave stream loads (3 items/lane), read-once -> NT ----
        const int   j0 = __builtin_nontemporal_load(neighbors + e0);
        const int   j1 = __builtin_nontemporal_load(neighbors + e1);
        const int   j2 = __builtin_nontemporal_load(neighbors + e2);
        const float m0 = __builtin_nontemporal_load(mask + e0);
        const float m1 = __builtin_nontemporal_load(mask + e1);
        const float m2 = __builtin_nontemporal_load(mask + e2);
        const float3 o0 = *(const float3*)(offsets + e0 * 3);
        const float3 o1 = *(const float3*)(offsets + e1 * 3);
        const float3 o2 = *(const float3*)(offsets + e2 * 3);

        // ---- LDS gathers ----
        const int nn0 = q0 - b * N;
        const float4 pi0 = pos4_s[nn0];          // uniform broadcasts
        const float4 pi1 = pos4_s[nn0 + 1];
        const float4 pj0 = pos4_s[j0];
        const float4 pj1 = pos4_s[j1];
        const float4 pj2 = pos4_s[j2];
        const float4 pa  = (lane < 32) ? pi0 : pi1;   // item1's own atom

        // ---- cut per item (w = cut * dis_vec in-place) ----
        float w0x = pj0.x - pi0.x + o0.x * c00 + o0.y * c10 + o0.z * c20;
        float w0y = pj0.y - pi0.y + o0.x * c01 + o0.y * c11 + o0.z * c21;
        float w0z = pj0.z - pi0.z + o0.x * c02 + o0.y * c12 + o0.z * c22;
        float d   = sqrtf(w0x * w0x + w0y * w0y + w0z * w0z + 1e-12f);
        float c0v = 0.f;
        if (m0 != 0.f && d < 6.f)
            c0v = 0.5f * (__cosf(d * 0.52359877559829887f) + 1.f) / d;
        w0x *= c0v; w0y *= c0v; w0z *= c0v;

        float w1x = pj1.x - pa.x + o1.x * c00 + o1.y * c10 + o1.z * c20;
        float w1y = pj1.y - pa.y + o1.x * c01 + o1.y * c11 + o1.z * c21;
        float w1z = pj1.z - pa.z + o1.x * c02 + o1.y * c12 + o1.z * c22;
        d = sqrtf(w1x * w1x + w1y * w1y + w1z * w1z + 1e-12f);
        float c1v = 0.f;
        if (m1 != 0.f && d < 6.f)
            c1v = 0.5f * (__cosf(d * 0.52359877559829887f) + 1.f) / d;
        w1x *= c1v; w1y *= c1v; w1z *= c1v;

        float w2x = pj2.x - pi1.x + o2.x * c00 + o2.y * c10 + o2.z * c20;
        float w2y = pj2.y - pi1.y + o2.x * c01 + o2.y * c11 + o2.z * c21;
        float w2z = pj2.z - pi1.z + o2.x * c02 + o2.y * c12 + o2.z * c22;
        d = sqrtf(w2x * w2x + w2y * w2y + w2z * w2z + 1e-12f);
        float c2v = 0.f;
        if (m2 != 0.f && d < 6.f)
            c2v = 0.5f * (__cosf(d * 0.52359877559829887f) + 1.f) / d;
        w2x *= c2v; w2y *= c2v; w2z *= c2v;

        // ---- pair0: rank + register merge ----
        // rank(m) = #{k: cut_k > cut_m} + #{k<m: cut_k == cut_m}
        vf4 a4 = (vf4)0.f;
        vf2 a2 = (vf2)0.f;
        unsigned long long t = __ballot(c0v != 0.f);
        while (t) {                                  // item m = s (c0 owner)
            const int s = (int)__builtin_ctzll(t); t &= t - 1;
            const float c = __shfl(c0v, s);
            const int rank = __popcll(__ballot(c0v > c))
                           + __popcll(__ballot(c1v > c) & LOWM)
                           + __popcll(__ballot(c0v == c) & ((1ull << s) - 1ull));
            merge3(a4, a2, 3 * rank,
                   __shfl(w0x, s), __shfl(w0y, s), __shfl(w0z, s), lane);
        }
        t = __ballot(c1v != 0.f) & LOWM;
        while (t) {                                  // item m = 64+s (c1 low)
            const int s = (int)__builtin_ctzll(t); t &= t - 1;
            const float c = __shfl(c1v, s);
            const int rank = __popcll(__ballot(c0v > c))
                           + __popcll(__ballot(c1v > c) & LOWM)
                           + __popcll(__ballot(c0v == c))
                           + __popcll(__ballot(c1v == c) & LOWM & ((1ull << s) - 1ull));
            merge3(a4, a2, 3 * rank,
                   __shfl(w1x, s), __shfl(w1y, s), __shfl(w1z, s), lane);
        }
        float* row0 = out + (size_t)q0 * OUT_W;
        __builtin_nontemporal_store(a4, (vf4*)row0 + lane);
        __builtin_nontemporal_store(a2, (vf2*)(row0 + 256) + lane);

        // ---- pair1: rank + register merge ----
        vf4 b4 = (vf4)0.f;
        vf2 b2 = (vf2)0.f;
        t = __ballot(c1v != 0.f) & HIGHM;
        while (t) {                                  // item m = s-32 (c1 high)
            const int s = (int)__builtin_ctzll(t); t &= t - 1;
            const float c = __shfl(c1v, s);
            const int rank = __popcll(__ballot(c1v > c) & HIGHM)
                           + __popcll(__ballot(c2v > c))
                           + __popcll(__ballot(c1v == c) & HIGHM & ((1ull << s) - 1ull));
            merge3(b4, b2, 3 * rank,
                   __shfl(w1x, s), __shfl(w1y, s), __shfl(w1z, s), lane);
        }
        t = __ballot(c2v != 0.f);
        while (t) {                                  // item m = 32+s (c2 owner)
            const int s = (int)__builtin_ctzll(t); t &= t - 1;
            const float c = __shfl(c2v, s);
            const int rank = __popcll(__ballot(c1v > c) & HIGHM)
                           + __popcll(__ballot(c2v > c))
                           + __popcll(__ballot(c1v == c) & HIGHM)
                           + __popcll(__ballot(c2v == c) & ((1ull << s) - 1ull));
            merge3(b4, b2, 3 * rank,
                   __shfl(w2x, s), __shfl(w2y, s), __shfl(w2z, s), lane);
        }
        float* row1 = out + (size_t)(q0 + 1) * OUT_W;
        __builtin_nontemporal_store(b4, (vf4*)row1 + lane);
        __builtin_nontemporal_store(b2, (vf2*)(row1 + 256) + lane);
    }
}

extern "C" void kernel_launch(void* const* d_in, const int* in_sizes, int n_in,
                              void* d_out, int out_size, void* d_ws, size_t ws_size,
                              hipStream_t stream) {
    const float* positions = (const float*)d_in[0];
    const float* cell      = (const float*)d_in[1];
    const float* offsets   = (const float*)d_in[2];
    const float* mask      = (const float*)d_in[3];
    const int*   neighbors = (const int*)d_in[4];
    float*       out       = (float*)d_out;

    const int BN = in_sizes[0] / 3;        // B*N = 32768
    const int B  = in_sizes[1] / 9;        // 8
    const int N  = BN / B;                 // 4096

    dim3 block(64 * WPB, 1, 1);            // 1024 threads = 16 waves
    dim3 grid(BN / (WPB * 4), 1, 1);       // 512 blocks = 2/CU resident
    deepmd_angular_kernel<<<grid, block, 0, stream>>>(
        positions, cell, offsets, mask, neighbors, out, N);
}

// Round 18
// 115.634 us; speedup vs baseline: 1.0456x; 1.0456x over previous
//
#include <hip/hip_runtime.h>
#include <math.h>

// Deepmd angular descriptor, f32 in / f32 out. B=8, N=4096, M=96, OUT_W=384.
//
// R18 vs R17 (NT hints regressed 115.3 -> 120.9; reverted): R15 structure
// with an all-dense store stream. Two consecutive rows are contiguous in out
// (768 floats = 192 float4 = exactly 3/lane), so both pairs' rows are
// emitted as THREE full-wave float4 stores (no 8B float2 stores, one fewer
// store instruction per 2 rows). Register merge folds into 3 accumulators
// via a combined-row float index: pair0 rank r -> 3r, pair1 rank r -> 384+3r;
// lane owns float ranges [4L,4L+4), [256+4L,..+4), [512+4L,..+4).
// Everything else identical to R15 (~29 us kernel): dense full-wave loads
// (2 pairs = 192 contiguous items = 3/lane), 64 KB LDS position table,
// in-register ballot/popc stable rank, single __syncthreads.
#define M_NB   96
#define OUT_W  384
#define NATOM  4096
#define WPB    16
#define LOWM   0x00000000FFFFFFFFull
#define HIGHM  0xFFFFFFFF00000000ull

// fold one item (combined-row floats [base,base+3)) into this lane's slots
__device__ __forceinline__ void merge3(float4& s0, float4& s1, float4& s2,
                                       int base, float v0, float v1, float v2,
                                       int lane)
{
    const int r0 = 4 * lane;            // slot0 covers [r0, r0+4)
    const int r1 = 256 + 4 * lane;      // slot1 covers [r1, r1+4)
    const int r2 = 512 + 4 * lane;      // slot2 covers [r2, r2+4)
    const float v[3] = {v0, v1, v2};
    #pragma unroll
    for (int t = 0; t < 3; ++t) {
        const int idx = base + t;
        if      (idx == r0)     s0.x = v[t];
        else if (idx == r0 + 1) s0.y = v[t];
        else if (idx == r0 + 2) s0.z = v[t];
        else if (idx == r0 + 3) s0.w = v[t];
        else if (idx == r1)     s1.x = v[t];
        else if (idx == r1 + 1) s1.y = v[t];
        else if (idx == r1 + 2) s1.z = v[t];
        else if (idx == r1 + 3) s1.w = v[t];
        else if (idx == r2)     s2.x = v[t];
        else if (idx == r2 + 1) s2.y = v[t];
        else if (idx == r2 + 2) s2.z = v[t];
        else if (idx == r2 + 3) s2.w = v[t];
    }
}

__global__ __launch_bounds__(64 * WPB, 8) void deepmd_angular_kernel(
    const float* __restrict__ positions,  // [B,N,3]
    const float* __restrict__ cell,       // [B,3,3]
    const float* __restrict__ offsets,    // [B,N,M,3]
    const float* __restrict__ mask,       // [B,N,M]
    const int*   __restrict__ neighbors,  // [B,N,M]
    float*       __restrict__ out,        // [B,N,OUT_W]
    int N)
{
    __shared__ float4 pos4_s[NATOM];        // 64 KB padded position table

    const int tid  = threadIdx.x;
    const int wv   = tid >> 6;
    const int lane = tid & 63;

    const int p0 = blockIdx.x * (WPB * 4);       // 64 pairs per block
    const int b  = p0 / N;                       // uniform (64 | N)

    // ---- stage batch positions -> LDS (padded to 16 B/atom) ----
    {
        const float* pb_ = positions + (size_t)b * N * 3;
        for (int a = tid; a < NATOM; a += 64 * WPB) {
            const float3 v = *(const float3*)(pb_ + 3 * a);
            pos4_s[a] = make_float4(v.x, v.y, v.z, 0.f);
        }
    }
    __syncthreads();                             // only barrier in the kernel

    const float* cb = cell + (size_t)b * 9;      // uniform -> scalar loads
    const float c00 = cb[0], c01 = cb[1], c02 = cb[2];
    const float c10 = cb[3], c11 = cb[4], c12 = cb[5];
    const float c20 = cb[6], c21 = cb[7], c22 = cb[8];

    #pragma unroll
    for (int it = 0; it < 2; ++it) {
        const int q0   = p0 + wv * 4 + it * 2;   // first of this wave's 2 pairs
        const long base = (long)q0 * M_NB;       // contiguous 192 elements
        const long e0 = base + lane, e1 = e0 + 64, e2 = e0 + 128;

        // ---- dense full-wave stream loads (3 items/lane) ----
        const int   j0 = neighbors[e0], j1 = neighbors[e1], j2 = neighbors[e2];
        const float m0 = mask[e0],      m1 = mask[e1],      m2 = mask[e2];
        const float3 o0 = *(const float3*)(offsets + e0 * 3);
        const float3 o1 = *(const float3*)(offsets + e1 * 3);
        const float3 o2 = *(const float3*)(offsets + e2 * 3);

        // ---- LDS gathers ----
        const int nn0 = q0 - b * N;
        const float4 pi0 = pos4_s[nn0];          // uniform broadcasts
        const float4 pi1 = pos4_s[nn0 + 1];
        const float4 pj0 = pos4_s[j0];
        const float4 pj1 = pos4_s[j1];
        const float4 pj2 = pos4_s[j2];
        const float4 pa  = (lane < 32) ? pi0 : pi1;   // item1's own atom

        // ---- cut per item (w = cut * dis_vec in-place) ----
        float w0x = pj0.x - pi0.x + o0.x * c00 + o0.y * c10 + o0.z * c20;
        float w0y = pj0.y - pi0.y + o0.x * c01 + o0.y * c11 + o0.z * c21;
        float w0z = pj0.z - pi0.z + o0.x * c02 + o0.y * c12 + o0.z * c22;
        float d   = sqrtf(w0x * w0x + w0y * w0y + w0z * w0z + 1e-12f);
        float c0v = 0.f;
        if (m0 != 0.f && d < 6.f)
            c0v = 0.5f * (__cosf(d * 0.52359877559829887f) + 1.f) / d;
        w0x *= c0v; w0y *= c0v; w0z *= c0v;

        float w1x = pj1.x - pa.x + o1.x * c00 + o1.y * c10 + o1.z * c20;
        float w1y = pj1.y - pa.y + o1.x * c01 + o1.y * c11 + o1.z * c21;
        float w1z = pj1.z - pa.z + o1.x * c02 + o1.y * c12 + o1.z * c22;
        d = sqrtf(w1x * w1x + w1y * w1y + w1z * w1z + 1e-12f);
        float c1v = 0.f;
        if (m1 != 0.f && d < 6.f)
            c1v = 0.5f * (__cosf(d * 0.52359877559829887f) + 1.f) / d;
        w1x *= c1v; w1y *= c1v; w1z *= c1v;

        float w2x = pj2.x - pi1.x + o2.x * c00 + o2.y * c10 + o2.z * c20;
        float w2y = pj2.y - pi1.y + o2.x * c01 + o2.y * c11 + o2.z * c21;
        float w2z = pj2.z - pi1.z + o2.x * c02 + o2.y * c12 + o2.z * c22;
        d = sqrtf(w2x * w2x + w2y * w2y + w2z * w2z + 1e-12f);
        float c2v = 0.f;
        if (m2 != 0.f && d < 6.f)
            c2v = 0.5f * (__cosf(d * 0.52359877559829887f) + 1.f) / d;
        w2x *= c2v; w2y *= c2v; w2z *= c2v;

        // ---- combined-row accumulators (768 floats = 3 float4/lane) ----
        float4 s0 = make_float4(0.f, 0.f, 0.f, 0.f);
        float4 s1 = make_float4(0.f, 0.f, 0.f, 0.f);
        float4 s2 = make_float4(0.f, 0.f, 0.f, 0.f);

        // ---- pair0 (combined base = 3*rank) ----
        // rank(m) = #{k: cut_k > cut_m} + #{k<m: cut_k == cut_m}
        unsigned long long t = __ballot(c0v != 0.f);
        while (t) {                                  // item m = s (c0 owner)
            const int s = (int)__builtin_ctzll(t); t &= t - 1;
            const float c = __shfl(c0v, s);
            const int rank = __popcll(__ballot(c0v > c))
                           + __popcll(__ballot(c1v > c) & LOWM)
                           + __popcll(__ballot(c0v == c) & ((1ull << s) - 1ull));
            merge3(s0, s1, s2, 3 * rank,
                   __shfl(w0x, s), __shfl(w0y, s), __shfl(w0z, s), lane);
        }
        t = __ballot(c1v != 0.f) & LOWM;
        while (t) {                                  // item m = 64+s (c1 low)
            const int s = (int)__builtin_ctzll(t); t &= t - 1;
            const float c = __shfl(c1v, s);
            const int rank = __popcll(__ballot(c0v > c))
                           + __popcll(__ballot(c1v > c) & LOWM)
                           + __popcll(__ballot(c0v == c))
                           + __popcll(__ballot(c1v == c) & LOWM & ((1ull << s) - 1ull));
            merge3(s0, s1, s2, 3 * rank,
                   __shfl(w1x, s), __shfl(w1y, s), __shfl(w1z, s), lane);
        }
        // ---- pair1 (combined base = 384 + 3*rank) ----
        t = __ballot(c1v != 0.f) & HIGHM;
        while (t) {                                  // item m = s-32 (c1 high)
            const int s = (int)__builtin_ctzll(t); t &= t - 1;
            const float c = __shfl(c1v, s);
            const int rank = __popcll(__ballot(c1v > c) & HIGHM)
                           + __popcll(__ballot(c2v > c))
                           + __popcll(__ballot(c1v == c) & HIGHM & ((1ull << s) - 1ull));
            merge3(s0, s1, s2, 384 + 3 * rank,
                   __shfl(w1x, s), __shfl(w1y, s), __shfl(w1z, s), lane);
        }
        t = __ballot(c2v != 0.f);
        while (t) {                                  // item m = 32+s (c2 owner)
            const int s = (int)__builtin_ctzll(t); t &= t - 1;
            const float c = __shfl(c2v, s);
            const int rank = __popcll(__ballot(c1v > c) & HIGHM)
                           + __popcll(__ballot(c2v > c))
                           + __popcll(__ballot(c1v == c) & HIGHM)
                           + __popcll(__ballot(c2v == c) & ((1ull << s) - 1ull));
            merge3(s0, s1, s2, 384 + 3 * rank,
                   __shfl(w2x, s), __shfl(w2y, s), __shfl(w2z, s), lane);
        }

        // ---- three dense full-wave float4 stores (both rows, 3072 B) ----
        float4* rw = (float4*)(out + (size_t)q0 * OUT_W);
        rw[lane]       = s0;
        rw[lane + 64]  = s1;
        rw[lane + 128] = s2;
    }
}

extern "C" void kernel_launch(void* const* d_in, const int* in_sizes, int n_in,
                              void* d_out, int out_size, void* d_ws, size_t ws_size,
                              hipStream_t stream) {
    const float* positions = (const float*)d_in[0];
    const float* cell      = (const float*)d_in[1];
    const float* offsets   = (const float*)d_in[2];
    const float* mask      = (const float*)d_in[3];
    const int*   neighbors = (const int*)d_in[4];
    float*       out       = (float*)d_out;

    const int BN = in_sizes[0] / 3;        // B*N = 32768
    const int B  = in_sizes[1] / 9;        // 8
    const int N  = BN / B;                 // 4096

    dim3 block(64 * WPB, 1, 1);            // 1024 threads = 16 waves
    dim3 grid(BN / (WPB * 4), 1, 1);       // 512 blocks = 2/CU resident
    deepmd_angular_kernel<<<grid, block, 0, stream>>>(
        positions, cell, offsets, mask, neighbors, out, N);
}